// Round 12
// baseline (180.037 us; speedup 1.0000x reference)
//
#include <hip/hip_runtime.h>
#include <math.h>

// Problem constants: B=2, S=2048, D=1024, H=16, HD=64
#define BB 2
#define SS 2048
#define DD 1024
#define HH 16
#define HD 64
#define MM (BB * SS)   // 4096 rows in flattened [B*S, D]

typedef __bf16 bf16;
typedef __attribute__((ext_vector_type(8))) __bf16 bf16x8;
typedef __attribute__((ext_vector_type(4))) __bf16 bf16x4;
typedef __attribute__((ext_vector_type(4))) short short4v;
typedef __attribute__((ext_vector_type(4))) float f32x4;

#if __has_builtin(__builtin_amdgcn_exp2f)
#define EXP2F(x) __builtin_amdgcn_exp2f(x)
#else
#define EXP2F(x) exp2f(x)
#endif

// PV MFMA: 16x16x16 so the P B-fragment (k = quad*4+j) matches St's C/D
// layout (key = quad*4+r) exactly -> P stays in registers, no LDS round-trip.
__device__ __forceinline__ f32x4 pv_mfma16(bf16x4 a, short4v b, f32x4 c) {
    return __builtin_amdgcn_mfma_f32_16x16x16bf16_1k(
        __builtin_bit_cast(short4v, a), b, c, 0, 0, 0);
}

// async global->LDS, 16 B per lane. lds dest = wave-uniform base + lane*16.
__device__ __forceinline__ void gld_lds16(const void* g, void* l) {
    __builtin_amdgcn_global_load_lds(
        (const __attribute__((address_space(1))) void*)g,
        (__attribute__((address_space(3))) void*)l, 16, 0, 0);
}

// ---------------------------------------------------------------------------
// prep: z<4 -> transpose+cast weight z (W[K,N] fp32 -> Wt[N,K] bf16);
//       z>=4 -> flat cast x fp32 -> bf16 (8 elems/thread).
// grid (32, 32, 6)
// ---------------------------------------------------------------------------
__global__ __launch_bounds__(256) void prep(
    const float* __restrict__ x,
    const float* __restrict__ W0, const float* __restrict__ W1,
    const float* __restrict__ W2, const float* __restrict__ W3,
    bf16* __restrict__ xb, bf16* __restrict__ Wt)
{
    __shared__ float tile[32][33];
    const int z = blockIdx.z;
    if (z < 4) {
        const float* W = (z == 0) ? W0 : (z == 1) ? W1 : (z == 2) ? W2 : W3;
        bf16* O = Wt + (size_t)z * DD * DD;
        const int tx = threadIdx.x & 31, ty = threadIdx.x >> 5;
        const int k0 = blockIdx.y * 32, n0 = blockIdx.x * 32;
#pragma unroll
        for (int i = 0; i < 4; ++i)
            tile[ty + i * 8][tx] = W[(size_t)(k0 + ty + i * 8) * DD + n0 + tx];
        __syncthreads();
#pragma unroll
        for (int i = 0; i < 4; ++i)
            O[(size_t)(n0 + ty + i * 8) * DD + k0 + tx] = (bf16)tile[tx][ty + i * 8];
    } else {
        const int lb = (z - 4) * 1024 + blockIdx.y * 32 + blockIdx.x;
        const size_t i = ((size_t)lb * 256 + threadIdx.x) * 8;
        const float4 a = *(const float4*)(x + i);
        const float4 b = *(const float4*)(x + i + 4);
        bf16x8 o;
        o[0] = (bf16)a.x; o[1] = (bf16)a.y; o[2] = (bf16)a.z; o[3] = (bf16)a.w;
        o[4] = (bf16)b.x; o[5] = (bf16)b.y; o[6] = (bf16)b.z; o[7] = (bf16)b.w;
        *(bf16x8*)(xb + i) = o;
    }
}

// ---------------------------------------------------------------------------
// MFMA GEMM core v2 (128x128 tile, 4 waves, BK=32 double-buffer, counted
// vmcnt, XOR swizzle). template SWAP: if 1, compute C^T via mfma(b,a) so the
// accumulator's r-direction lands on the N axis (packed N-contiguous stores).
//   SWAP=0: acc[mi][ni][r] = C[bm + wr*64+mi*16+quad*4+r][bn + wc*64+ni*16+l16]
//   SWAP=1: acc[mi][ni][r] = C[bm + wr*64+mi*16+l16][bn + wc*64+ni*16+quad*4+r]
// ---------------------------------------------------------------------------
template <int SWAP>
__device__ __forceinline__ void mfma_core(
    const bf16* __restrict__ A, const bf16* __restrict__ Bt,
    int bm, int bn, int K, bf16* As, bf16* Bs, f32x4 (&acc)[4][4])
{
    const int t = threadIdx.x;
    const int w = t >> 6;
    const int l16 = t & 15, quad = (t >> 4) & 3;
    const int wr = w >> 1, wc = w & 1;
    const int arow = t >> 2;
    const int achk = (((t & 3) ^ ((t >> 3) & 3)) << 3);

    const bf16* gA = A + (size_t)(bm + arow) * K + achk;
    const bf16* gB = Bt + (size_t)(bn + arow) * K + achk;
    bf16* lA = As + w * 512;
    bf16* lB = Bs + w * 512;

    const int swz = (l16 >> 1) & 3;
    int offA[4], offB[4];
#pragma unroll
    for (int i = 0; i < 4; ++i) {
        offA[i] = (wr * 64 + i * 16 + l16) * 32 + ((quad ^ swz) << 3);
        offB[i] = (wc * 64 + i * 16 + l16) * 32 + ((quad ^ swz) << 3);
    }

#define GSTAGE(BUF, KO) do {                                                  \
        gld_lds16(gA + (KO),                  lA + (BUF) * 4096);             \
        gld_lds16(gA + (size_t)64 * K + (KO), lA + (BUF) * 4096 + 2048);      \
        gld_lds16(gB + (KO),                  lB + (BUF) * 4096);             \
        gld_lds16(gB + (size_t)64 * K + (KO), lB + (BUF) * 4096 + 2048);      \
    } while (0)

#define GCOMPUTE(BUF) do {                                                    \
        const bf16* Ab = As + (BUF) * 4096;                                   \
        const bf16* Bb = Bs + (BUF) * 4096;                                   \
        bf16x8 af[4], bv[4];                                                  \
        _Pragma("unroll")                                                     \
        for (int i = 0; i < 4; ++i) {                                         \
            af[i] = *(const bf16x8*)(Ab + offA[i]);                           \
            bv[i] = *(const bf16x8*)(Bb + offB[i]);                           \
        }                                                                     \
        _Pragma("unroll")                                                     \
        for (int mi = 0; mi < 4; ++mi)                                        \
            _Pragma("unroll")                                                 \
            for (int ni = 0; ni < 4; ++ni)                                    \
                acc[mi][ni] = SWAP                                            \
                    ? __builtin_amdgcn_mfma_f32_16x16x32_bf16(                \
                          bv[ni], af[mi], acc[mi][ni], 0, 0, 0)               \
                    : __builtin_amdgcn_mfma_f32_16x16x32_bf16(                \
                          af[mi], bv[ni], acc[mi][ni], 0, 0, 0);              \
    } while (0)

#define GBAR() do {                                                           \
        asm volatile("s_barrier" ::: "memory");                               \
        __builtin_amdgcn_sched_barrier(0);                                    \
    } while (0)

    GSTAGE(0, 0);
    const int nk = K >> 5;
    for (int kt = 0; kt < nk; kt += 2) {
        GSTAGE(1, (kt + 1) << 5);
        asm volatile("s_waitcnt vmcnt(4)" ::: "memory");
        GBAR();
        GCOMPUTE(0);
        asm volatile("s_waitcnt lgkmcnt(0)" ::: "memory");
        GBAR();
        if (kt + 2 < nk) {
            GSTAGE(0, (kt + 2) << 5);
            asm volatile("s_waitcnt vmcnt(4)" ::: "memory");
        } else {
            asm volatile("s_waitcnt vmcnt(0)" ::: "memory");
        }
        GBAR();
        GCOMPUTE(1);
        asm volatile("s_waitcnt lgkmcnt(0)" ::: "memory");
        GBAR();
    }
#undef GBAR
#undef GCOMPUTE
#undef GSTAGE
}

// ---------------------------------------------------------------------------
// QKV fused GEMM (v2 core + packed epilogues):
//   z<2 (Q,K head-major): SWAP core -> r on hd -> bf16x4 stores.
//   z==2 (V^T): normal core -> r on s -> bf16x4 stores.
// Q pre-scaled by 0.125*log2(e) so attention uses raw exp2.
// ---------------------------------------------------------------------------
__global__ __launch_bounds__(256) void gemm_qkv(
    const bf16* __restrict__ xb, const bf16* __restrict__ Wt,
    bf16* __restrict__ Qb, bf16* __restrict__ Kb, bf16* __restrict__ Vb)
{
    __shared__ __align__(16) bf16 As[2 * 128 * 32];
    __shared__ __align__(16) bf16 Bs[2 * 128 * 32];
    const int bm = blockIdx.y * 128, bn = blockIdx.x * 128, z = blockIdx.z;

    const int t = threadIdx.x;
    const int w = t >> 6, l16 = t & 15, quad = (t >> 4) & 3;
    const int wr = w >> 1, wc = w & 1;

    f32x4 acc[4][4] = {};
    if (z < 2) {
        mfma_core<1>(xb, Wt + (size_t)z * DD * DD, bm, bn, DD, As, Bs, acc);
        bf16* outp = (z == 0) ? Qb : Kb;
        const float scl = (z == 0) ? 0.18033688011f : 1.0f;  // 0.125*log2(e)
#pragma unroll
        for (int mi = 0; mi < 4; ++mi) {
            const int srow = bm + wr * 64 + mi * 16 + l16;    // M = (b,s)
            const int b = srow >> 11, s = srow & (SS - 1);
#pragma unroll
            for (int ni = 0; ni < 4; ++ni) {
                const int colb = bn + wc * 64 + ni * 16 + quad * 4;
                const int h = colb >> 6, hd = colb & 63;      // hd..hd+3
                bf16x4 o;
#pragma unroll
                for (int r = 0; r < 4; ++r) o[r] = (bf16)(acc[mi][ni][r] * scl);
                *(bf16x4*)(outp + ((size_t)((b * HH + h) * SS + s)) * HD + hd) = o;
            }
        }
    } else {
        mfma_core<0>(xb, Wt + (size_t)2 * DD * DD, bm, bn, DD, As, Bs, acc);
#pragma unroll
        for (int mi = 0; mi < 4; ++mi) {
            const int srow0 = bm + wr * 64 + mi * 16 + quad * 4;  // s..s+3
            const int b = srow0 >> 11, s0 = srow0 & (SS - 1);
#pragma unroll
            for (int ni = 0; ni < 4; ++ni) {
                const int col = bn + wc * 64 + ni * 16 + l16;
                const int h = col >> 6, hd = col & 63;
                bf16x4 o;
#pragma unroll
                for (int r = 0; r < 4; ++r) o[r] = (bf16)acc[mi][ni][r];
                *(bf16x4*)(Vb + ((size_t)((b * HH + h) * HD + hd)) * SS + s0) = o;
            }
        }
    }
}

// ---------------------------------------------------------------------------
// Output projection: ctx(bf16) @ Wo^T + bo -> fp32 [M, D].
// SWAP core: float4 stores + float4 bias loads.
// ---------------------------------------------------------------------------
__global__ __launch_bounds__(256) void gemm_out(
    const bf16* __restrict__ ctx, const bf16* __restrict__ Wto,
    const float* __restrict__ bias, float* __restrict__ out)
{
    __shared__ __align__(16) bf16 As[2 * 128 * 32];
    __shared__ __align__(16) bf16 Bs[2 * 128 * 32];
    const int bm = blockIdx.y * 128, bn = blockIdx.x * 128;

    f32x4 acc[4][4] = {};
    mfma_core<1>(ctx, Wto, bm, bn, DD, As, Bs, acc);

    const int t = threadIdx.x;
    const int w = t >> 6, l16 = t & 15, quad = (t >> 4) & 3;
    const int wr = w >> 1, wc = w & 1;

#pragma unroll
    for (int mi = 0; mi < 4; ++mi) {
        const int row = bm + wr * 64 + mi * 16 + l16;
#pragma unroll
        for (int ni = 0; ni < 4; ++ni) {
            const int colb = bn + wc * 64 + ni * 16 + quad * 4;
            const float4 b4 = *(const float4*)(bias + colb);
            float4 o;
            o.x = acc[mi][ni][0] + b4.x;
            o.y = acc[mi][ni][1] + b4.y;
            o.z = acc[mi][ni][2] + b4.z;
            o.w = acc[mi][ni][3] + b4.w;
            *(float4*)(out + (size_t)row * DD + colb) = o;
        }
    }
}

// ---------------------------------------------------------------------------
// Flash attention v8: v6 skeleton (QBLK=128, 8 waves, 2-buffer K/V,
// __syncthreads pacing — proven best) + T15-style cross-tile software
// pipeline: PV(t-1) runs from REGISTER-held {pbr, avr} inside interval t,
// overlapping with QK(t) MFMAs and the V(t) register re-load. Breaks the
// serial QK->SM->PV chain without touching the sync/staging structure
// (v7's counted-vmcnt rewrite regressed; this keeps v6's guarantees:
// avr is lgkm-drained into registers before the sync that precedes the
// staging overwrite of its source buffer).
// ---------------------------------------------------------------------------
__global__ __launch_bounds__(512, 4) void attn_flash(
    const bf16* __restrict__ Q, const bf16* __restrict__ K,
    const bf16* __restrict__ Vt, bf16* __restrict__ ctx)
{
    __shared__ __align__(16) bf16 Ks[2][64 * 64];   // swizzled [key][d]
    __shared__ __align__(16) bf16 Vs[2][64 * 64];   // swizzled [d][key]

    const int t = threadIdx.x;
    const int w = t >> 6;                  // 0..7
    const int lane = t & 63;
    const int l16 = lane & 15, quad = lane >> 4;

    const int L  = blockIdx.x;
    const int bh = L & 31;                 // L%8 == bh%8 -> XCD locality
    const int slot = L >> 5;               // 0..15 q-group slot
    const int g = (slot < 8) ? 15 - slot : slot - 8;   // pair-sum const
    const int q0b = g * 128;
    const int q0w = q0b + w * 16;
    const int qrow = q0w + l16;
    const int nkt = 2 * g + 2;             // always even, >= 2

    const bf16* Qp = Q  + ((size_t)bh * SS + q0w) * HD;
    const bf16* Kp = K  + (size_t)bh * SS * HD;
    const bf16* Vp = Vt + (size_t)bh * HD * SS;

    // Q B-fragments (n = q0w + l16; k-chunks d=0..31, 32..63)
    const bf16x8 bQ0 = *(const bf16x8*)(Qp + l16 * HD + quad * 8);
    const bf16x8 bQ1 = *(const bf16x8*)(Qp + l16 * HD + 32 + quad * 8);

    // staging: wave w covers rows w*8..w*8+7 of K (keys) and V^T (d);
    // thread covers row = w*8 + (lane>>3), chunk slot cs = lane&7,
    // source chunk c = (cs - row)&7  (chunk' = (chunk+row)&7 swizzle)
    const int srow = w * 8 + (lane >> 3);
    const int c = ((lane & 7) - srow) & 7;
    const bf16* gK = Kp + (size_t)srow * HD + c * 8;
    const bf16* gV = Vp + (size_t)srow * SS + c * 8;
    bf16* const lK = &Ks[0][w * 512];
    bf16* const lV = &Vs[0][w * 512];

#define STAGE(BUF, KB) do {                                              \
        gld_lds16(gK + (size_t)(KB) * HD, lK + (BUF) * 4096);            \
        gld_lds16(gV + (KB),              lV + (BUF) * 4096);            \
    } while (0)

    // LDS read element-offsets, loop-invariant (16*mi == 0 mod 8 drops out)
    const int offK0 = l16 * 64 + ((quad + l16) & 7) * 8;
    const int offK1 = l16 * 64 + ((quad + 4 + l16) & 7) * 8;
    int offV[4];
#pragma unroll
    for (int mi = 0; mi < 4; ++mi)
        offV[mi] = l16 * 64 + ((((quad >> 1) + 2 * mi + l16) & 7) * 8)
                 + (quad & 1) * 4;

    const bf16* const KsB = &Ks[0][0];
    const bf16* const VsB = &Vs[0][0];

    f32x4 accO[4] = {{0,0,0,0},{0,0,0,0},{0,0,0,0},{0,0,0,0}};
    float Lr = 0.f;

    short4v pbr[4];      // P of previous tile (bf16x4 packs)
    bf16x4  avr[4][4];   // V fragments of previous tile, [mi][db]

    // PHASE: interval body for one tile. Order: QK(t) MFMAs -> PV(t-1)
    // MFMAs (independent; consumes pbr/avr) -> avr <- V(t) (overwrites) ->
    // mask+SM(t) -> pbr. DOPREV is a compile-time 0/1.
#define PHASE(BUF, KB, DOPREV) do {                                          \
        f32x4 St[4] = {{0,0,0,0},{0,0,0,0},{0,0,0,0},{0,0,0,0}};             \
        _Pragma("unroll")                                                    \
        for (int mi = 0; mi < 4; ++mi) {                                     \
            const bf16x8 a0 = *(const bf16x8*)(KsB + (BUF) * 4096            \
                                               + mi * 1024 + offK0);         \
            const bf16x8 a1 = *(const bf16x8*)(KsB + (BUF) * 4096            \
                                               + mi * 1024 + offK1);         \
            St[mi] = __builtin_amdgcn_mfma_f32_16x16x32_bf16(                \
                a0, bQ0, St[mi], 0, 0, 0);                                   \
            St[mi] = __builtin_amdgcn_mfma_f32_16x16x32_bf16(                \
                a1, bQ1, St[mi], 0, 0, 0);                                   \
        }                                                                    \
        if (DOPREV) {                                                        \
            _Pragma("unroll")                                                \
            for (int mi = 0; mi < 4; ++mi)                                   \
                _Pragma("unroll")                                            \
                for (int db = 0; db < 4; ++db)                               \
                    accO[db] = pv_mfma16(avr[mi][db], pbr[mi], accO[db]);    \
        }                                                                    \
        _Pragma("unroll")                                                    \
        for (int mi = 0; mi < 4; ++mi)                                       \
            _Pragma("unroll")                                                \
            for (int db = 0; db < 4; ++db)                                   \
                avr[mi][db] = *(const bf16x4*)(VsB + (BUF) * 4096            \
                                               + db * 1024 + offV[mi]);      \
        if ((KB) + 63 > q0w) {                                               \
            _Pragma("unroll")                                                \
            for (int mi = 0; mi < 4; ++mi)                                   \
                _Pragma("unroll")                                            \
                for (int rr = 0; rr < 4; ++rr)                               \
                    if ((KB) + mi * 16 + quad * 4 + rr > qrow)               \
                        St[mi][rr] = -1e30f;                                 \
        }                                                                    \
        float rs = 0.f;                                                      \
        _Pragma("unroll")                                                    \
        for (int mi = 0; mi < 4; ++mi) {                                     \
            bf16x4 pk;                                                       \
            _Pragma("unroll")                                                \
            for (int rr = 0; rr < 4; ++rr) {                                 \
                const float p = EXP2F(St[mi][rr]);                           \
                rs += p;                                                     \
                pk[rr] = (bf16)p;                                            \
            }                                                                \
            pbr[mi] = __builtin_bit_cast(short4v, pk);                       \
        }                                                                    \
        rs += __shfl_xor(rs, 16);                                            \
        rs += __shfl_xor(rs, 32);                                            \
        Lr += rs;                                                            \
    } while (0)

#define PVFIN() do {                                                         \
        _Pragma("unroll")                                                    \
        for (int mi = 0; mi < 4; ++mi)                                       \
            _Pragma("unroll")                                                \
            for (int db = 0; db < 4; ++db)                                   \
                accO[db] = pv_mfma16(avr[mi][db], pbr[mi], accO[db]);        \
    } while (0)

    // ---- pipeline driver (same stage/sync placement as v6) -----------------
    // peeled first pair: tile0 (buf0, no prev), tile1 (buf1; last-tile-dead
    // for w<4 when nkt==2 — those waves finish tile0's PV in PVFIN)
    STAGE(0, 0);
    __syncthreads();                       // tile0 staged
    STAGE(1, 64);
    PHASE(0, 0, 0);
    __syncthreads();                       // tile1 staged
    if (nkt > 2) STAGE(0, 128);
    if (nkt > 2 || w >= 4) PHASE(1, 64, 1);

    int kb = 128;
    for (int kt = 2; kt < nkt; kt += 2) {
        __syncthreads();                   // buf0 (tile kt) staged
        STAGE(1, kb + 64);
        PHASE(0, kb, 1);
        __syncthreads();                   // buf1 (tile kt+1) staged
        if (kt + 2 < nkt) STAGE(0, kb + 128);
        if (kt + 2 < nkt || w >= 4) PHASE(1, kb + 64, 1);
        kb += 128;
    }
    PVFIN();                               // PV of the final live tile
#undef PVFIN
#undef PHASE
#undef STAGE

    // ---- epilogue ----------------------------------------------------------
    const float rinv = 1.0f / Lr;
    const int b = bh >> 4, h = bh & (HH - 1);
    bf16* op = ctx + ((size_t)(b * SS + q0w + l16)) * DD + h * HD;
#pragma unroll
    for (int db = 0; db < 4; ++db) {
        bf16x4 o;
#pragma unroll
        for (int rr = 0; rr < 4; ++rr) o[rr] = (bf16)(accO[db][rr] * rinv);
        *(bf16x4*)(op + db * 16 + quad * 4) = o;
    }
}

// ---------------------------------------------------------------------------
extern "C" void kernel_launch(void* const* d_in, const int* in_sizes, int n_in,
                              void* d_out, int out_size, void* d_ws, size_t ws_size,
                              hipStream_t stream)
{
    const float* x  = (const float*)d_in[0];
    const float* Wq = (const float*)d_in[1];
    const float* Wk = (const float*)d_in[2];
    const float* Wv = (const float*)d_in[3];
    const float* Wo = (const float*)d_in[4];
    const float* bo = (const float*)d_in[5];
    float* out = (float*)d_out;

    const size_t chunk = (size_t)MM * DD;
    bf16* xb  = (bf16*)d_ws;
    bf16* Wt  = xb + chunk;
    bf16* Qb  = Wt + 4 * (size_t)DD * DD;
    bf16* Kb  = Qb + chunk;
    bf16* Vb  = Kb + chunk;
    bf16* ctx = Vb + chunk;

    prep<<<dim3(32, 32, 6), dim3(256), 0, stream>>>(x, Wq, Wk, Wv, Wo, xb, Wt);

    gemm_qkv<<<dim3(DD / 128, MM / 128, 3), dim3(256), 0, stream>>>(xb, Wt, Qb, Kb, Vb);

    attn_flash<<<dim3(BB * HH * (SS / 128)), dim3(512), 0, stream>>>(Qb, Kb, Vb, ctx);

    gemm_out<<<dim3(DD / 128, MM / 128), dim3(256), 0, stream>>>(
        ctx, Wt + 3 * (size_t)DD * DD, bo, out);
}

// Round 13
// 177.773 us; speedup vs baseline: 1.0127x; 1.0127x over previous
//
#include <hip/hip_runtime.h>
#include <math.h>

// Problem constants: B=2, S=2048, D=1024, H=16, HD=64
#define BB 2
#define SS 2048
#define DD 1024
#define HH 16
#define HD 64
#define MM (BB * SS)   // 4096 rows in flattened [B*S, D]

typedef __bf16 bf16;
typedef __attribute__((ext_vector_type(8))) __bf16 bf16x8;
typedef __attribute__((ext_vector_type(4))) __bf16 bf16x4;
typedef __attribute__((ext_vector_type(4))) short short4v;
typedef __attribute__((ext_vector_type(4))) float f32x4;

#if __has_builtin(__builtin_amdgcn_exp2f)
#define EXP2F(x) __builtin_amdgcn_exp2f(x)
#else
#define EXP2F(x) exp2f(x)
#endif

// PV MFMA: 16x16x16 so the P B-fragment (k = quad*4+j) matches St's C/D
// layout (key = quad*4+r) exactly -> P stays in registers, no LDS round-trip.
__device__ __forceinline__ f32x4 pv_mfma16(bf16x4 a, short4v b, f32x4 c) {
    return __builtin_amdgcn_mfma_f32_16x16x16bf16_1k(
        __builtin_bit_cast(short4v, a), b, c, 0, 0, 0);
}

// async global->LDS, 16 B per lane. lds dest = wave-uniform base + lane*16.
__device__ __forceinline__ void gld_lds16(const void* g, void* l) {
    __builtin_amdgcn_global_load_lds(
        (const __attribute__((address_space(1))) void*)g,
        (__attribute__((address_space(3))) void*)l, 16, 0, 0);
}

// ---------------------------------------------------------------------------
// prep: z<4 -> transpose+cast weight z (W[K,N] fp32 -> Wt[N,K] bf16);
//       z>=4 -> flat cast x fp32 -> bf16 (8 elems/thread).
// grid (32, 32, 6)
// ---------------------------------------------------------------------------
__global__ __launch_bounds__(256) void prep(
    const float* __restrict__ x,
    const float* __restrict__ W0, const float* __restrict__ W1,
    const float* __restrict__ W2, const float* __restrict__ W3,
    bf16* __restrict__ xb, bf16* __restrict__ Wt)
{
    __shared__ float tile[32][33];
    const int z = blockIdx.z;
    if (z < 4) {
        const float* W = (z == 0) ? W0 : (z == 1) ? W1 : (z == 2) ? W2 : W3;
        bf16* O = Wt + (size_t)z * DD * DD;
        const int tx = threadIdx.x & 31, ty = threadIdx.x >> 5;
        const int k0 = blockIdx.y * 32, n0 = blockIdx.x * 32;
#pragma unroll
        for (int i = 0; i < 4; ++i)
            tile[ty + i * 8][tx] = W[(size_t)(k0 + ty + i * 8) * DD + n0 + tx];
        __syncthreads();
#pragma unroll
        for (int i = 0; i < 4; ++i)
            O[(size_t)(n0 + ty + i * 8) * DD + k0 + tx] = (bf16)tile[tx][ty + i * 8];
    } else {
        const int lb = (z - 4) * 1024 + blockIdx.y * 32 + blockIdx.x;
        const size_t i = ((size_t)lb * 256 + threadIdx.x) * 8;
        const float4 a = *(const float4*)(x + i);
        const float4 b = *(const float4*)(x + i + 4);
        bf16x8 o;
        o[0] = (bf16)a.x; o[1] = (bf16)a.y; o[2] = (bf16)a.z; o[3] = (bf16)a.w;
        o[4] = (bf16)b.x; o[5] = (bf16)b.y; o[6] = (bf16)b.z; o[7] = (bf16)b.w;
        *(bf16x8*)(xb + i) = o;
    }
}

// ---------------------------------------------------------------------------
// MFMA GEMM core v2 (128x128 tile, 4 waves, BK=32 double-buffer, counted
// vmcnt, XOR swizzle). template SWAP: if 1, compute C^T via mfma(b,a) so the
// accumulator's r-direction lands on the N axis (packed N-contiguous stores).
//   SWAP=0: acc[mi][ni][r] = C[bm + wr*64+mi*16+quad*4+r][bn + wc*64+ni*16+l16]
//   SWAP=1: acc[mi][ni][r] = C[bm + wr*64+mi*16+l16][bn + wc*64+ni*16+quad*4+r]
// ---------------------------------------------------------------------------
template <int SWAP>
__device__ __forceinline__ void mfma_core(
    const bf16* __restrict__ A, const bf16* __restrict__ Bt,
    int bm, int bn, int K, bf16* As, bf16* Bs, f32x4 (&acc)[4][4])
{
    const int t = threadIdx.x;
    const int w = t >> 6;
    const int l16 = t & 15, quad = (t >> 4) & 3;
    const int wr = w >> 1, wc = w & 1;
    const int arow = t >> 2;
    const int achk = (((t & 3) ^ ((t >> 3) & 3)) << 3);

    const bf16* gA = A + (size_t)(bm + arow) * K + achk;
    const bf16* gB = Bt + (size_t)(bn + arow) * K + achk;
    bf16* lA = As + w * 512;
    bf16* lB = Bs + w * 512;

    const int swz = (l16 >> 1) & 3;
    int offA[4], offB[4];
#pragma unroll
    for (int i = 0; i < 4; ++i) {
        offA[i] = (wr * 64 + i * 16 + l16) * 32 + ((quad ^ swz) << 3);
        offB[i] = (wc * 64 + i * 16 + l16) * 32 + ((quad ^ swz) << 3);
    }

#define GSTAGE(BUF, KO) do {                                                  \
        gld_lds16(gA + (KO),                  lA + (BUF) * 4096);             \
        gld_lds16(gA + (size_t)64 * K + (KO), lA + (BUF) * 4096 + 2048);      \
        gld_lds16(gB + (KO),                  lB + (BUF) * 4096);             \
        gld_lds16(gB + (size_t)64 * K + (KO), lB + (BUF) * 4096 + 2048);      \
    } while (0)

#define GCOMPUTE(BUF) do {                                                    \
        const bf16* Ab = As + (BUF) * 4096;                                   \
        const bf16* Bb = Bs + (BUF) * 4096;                                   \
        bf16x8 af[4], bv[4];                                                  \
        _Pragma("unroll")                                                     \
        for (int i = 0; i < 4; ++i) {                                         \
            af[i] = *(const bf16x8*)(Ab + offA[i]);                           \
            bv[i] = *(const bf16x8*)(Bb + offB[i]);                           \
        }                                                                     \
        _Pragma("unroll")                                                     \
        for (int mi = 0; mi < 4; ++mi)                                        \
            _Pragma("unroll")                                                 \
            for (int ni = 0; ni < 4; ++ni)                                    \
                acc[mi][ni] = SWAP                                            \
                    ? __builtin_amdgcn_mfma_f32_16x16x32_bf16(                \
                          bv[ni], af[mi], acc[mi][ni], 0, 0, 0)               \
                    : __builtin_amdgcn_mfma_f32_16x16x32_bf16(                \
                          af[mi], bv[ni], acc[mi][ni], 0, 0, 0);              \
    } while (0)

#define GBAR() do {                                                           \
        asm volatile("s_barrier" ::: "memory");                               \
        __builtin_amdgcn_sched_barrier(0);                                    \
    } while (0)

    GSTAGE(0, 0);
    const int nk = K >> 5;
    for (int kt = 0; kt < nk; kt += 2) {
        GSTAGE(1, (kt + 1) << 5);
        asm volatile("s_waitcnt vmcnt(4)" ::: "memory");
        GBAR();
        GCOMPUTE(0);
        asm volatile("s_waitcnt lgkmcnt(0)" ::: "memory");
        GBAR();
        if (kt + 2 < nk) {
            GSTAGE(0, (kt + 2) << 5);
            asm volatile("s_waitcnt vmcnt(4)" ::: "memory");
        } else {
            asm volatile("s_waitcnt vmcnt(0)" ::: "memory");
        }
        GBAR();
        GCOMPUTE(1);
        asm volatile("s_waitcnt lgkmcnt(0)" ::: "memory");
        GBAR();
    }
#undef GBAR
#undef GCOMPUTE
#undef GSTAGE
}

// ---------------------------------------------------------------------------
// QKV fused GEMM (v2 core + packed epilogues):
//   z<2 (Q,K head-major): SWAP core -> r on hd -> bf16x4 stores.
//   z==2 (V^T): normal core -> r on s -> bf16x4 stores.
// Q pre-scaled by 0.125*log2(e) so attention uses raw exp2.
// ---------------------------------------------------------------------------
__global__ __launch_bounds__(256) void gemm_qkv(
    const bf16* __restrict__ xb, const bf16* __restrict__ Wt,
    bf16* __restrict__ Qb, bf16* __restrict__ Kb, bf16* __restrict__ Vb)
{
    __shared__ __align__(16) bf16 As[2 * 128 * 32];
    __shared__ __align__(16) bf16 Bs[2 * 128 * 32];
    const int bm = blockIdx.y * 128, bn = blockIdx.x * 128, z = blockIdx.z;

    const int t = threadIdx.x;
    const int w = t >> 6, l16 = t & 15, quad = (t >> 4) & 3;
    const int wr = w >> 1, wc = w & 1;

    f32x4 acc[4][4] = {};
    if (z < 2) {
        mfma_core<1>(xb, Wt + (size_t)z * DD * DD, bm, bn, DD, As, Bs, acc);
        bf16* outp = (z == 0) ? Qb : Kb;
        const float scl = (z == 0) ? 0.18033688011f : 1.0f;  // 0.125*log2(e)
#pragma unroll
        for (int mi = 0; mi < 4; ++mi) {
            const int srow = bm + wr * 64 + mi * 16 + l16;    // M = (b,s)
            const int b = srow >> 11, s = srow & (SS - 1);
#pragma unroll
            for (int ni = 0; ni < 4; ++ni) {
                const int colb = bn + wc * 64 + ni * 16 + quad * 4;
                const int h = colb >> 6, hd = colb & 63;      // hd..hd+3
                bf16x4 o;
#pragma unroll
                for (int r = 0; r < 4; ++r) o[r] = (bf16)(acc[mi][ni][r] * scl);
                *(bf16x4*)(outp + ((size_t)((b * HH + h) * SS + s)) * HD + hd) = o;
            }
        }
    } else {
        mfma_core<0>(xb, Wt + (size_t)2 * DD * DD, bm, bn, DD, As, Bs, acc);
#pragma unroll
        for (int mi = 0; mi < 4; ++mi) {
            const int srow0 = bm + wr * 64 + mi * 16 + quad * 4;  // s..s+3
            const int b = srow0 >> 11, s0 = srow0 & (SS - 1);
#pragma unroll
            for (int ni = 0; ni < 4; ++ni) {
                const int col = bn + wc * 64 + ni * 16 + l16;
                const int h = col >> 6, hd = col & 63;
                bf16x4 o;
#pragma unroll
                for (int r = 0; r < 4; ++r) o[r] = (bf16)acc[mi][ni][r];
                *(bf16x4*)(Vb + ((size_t)((b * HH + h) * HD + hd)) * SS + s0) = o;
            }
        }
    }
}

// ---------------------------------------------------------------------------
// Output projection: ctx(bf16) @ Wo^T + bo -> fp32 [M, D].
// SWAP core: float4 stores + float4 bias loads.
// ---------------------------------------------------------------------------
__global__ __launch_bounds__(256) void gemm_out(
    const bf16* __restrict__ ctx, const bf16* __restrict__ Wto,
    const float* __restrict__ bias, float* __restrict__ out)
{
    __shared__ __align__(16) bf16 As[2 * 128 * 32];
    __shared__ __align__(16) bf16 Bs[2 * 128 * 32];
    const int bm = blockIdx.y * 128, bn = blockIdx.x * 128;

    f32x4 acc[4][4] = {};
    mfma_core<1>(ctx, Wto, bm, bn, DD, As, Bs, acc);

    const int t = threadIdx.x;
    const int w = t >> 6, l16 = t & 15, quad = (t >> 4) & 3;
    const int wr = w >> 1, wc = w & 1;

#pragma unroll
    for (int mi = 0; mi < 4; ++mi) {
        const int row = bm + wr * 64 + mi * 16 + l16;
#pragma unroll
        for (int ni = 0; ni < 4; ++ni) {
            const int colb = bn + wc * 64 + ni * 16 + quad * 4;
            const float4 b4 = *(const float4*)(bias + colb);
            float4 o;
            o.x = acc[mi][ni][0] + b4.x;
            o.y = acc[mi][ni][1] + b4.y;
            o.z = acc[mi][ni][2] + b4.z;
            o.w = acc[mi][ni][3] + b4.w;
            *(float4*)(out + (size_t)row * DD + colb) = o;
        }
    }
}

// ---------------------------------------------------------------------------
// Flash attention v6 (best measured: 44.4 us; session final): QBLK=128
// (8 waves, 512 threads). Per-wave work = 16 q-rows x 64 keys per tile
// (8 QK-MFMA + 16 PV-MFMA, register-resident P, static-max softmax, raw
// exp2 on pre-scaled Q). Double-buffered K/V, __syncthreads pacing.
// Rejected alternatives (measured): counted-vmcnt 3-buffer (51.6 us, R10),
// cross-tile register PV pipeline (45.9 us, R12), setprio/XCD-swizzle
// (noise, R9).
// ---------------------------------------------------------------------------
__global__ __launch_bounds__(512, 4) void attn_flash(
    const bf16* __restrict__ Q, const bf16* __restrict__ K,
    const bf16* __restrict__ Vt, bf16* __restrict__ ctx)
{
    __shared__ __align__(16) bf16 Ks[2][64 * 64];   // swizzled [key][d]
    __shared__ __align__(16) bf16 Vs[2][64 * 64];   // swizzled [d][key]

    const int t = threadIdx.x;
    const int w = t >> 6;                  // 0..7
    const int lane = t & 63;
    const int l16 = lane & 15, quad = lane >> 4;

    const int L  = blockIdx.x;
    const int bh = L & 31;                 // L%8 == bh%8 -> XCD locality
    const int slot = L >> 5;               // 0..15 q-group slot
    const int g = (slot < 8) ? 15 - slot : slot - 8;   // pair-sum const
    const int q0b = g * 128;
    const int q0w = q0b + w * 16;
    const int qrow = q0w + l16;
    const int nkt = 2 * g + 2;             // always even

    const bf16* Qp = Q  + ((size_t)bh * SS + q0w) * HD;
    const bf16* Kp = K  + (size_t)bh * SS * HD;
    const bf16* Vp = Vt + (size_t)bh * HD * SS;

    // Q B-fragments (n = q0w + l16; k-chunks d=0..31, 32..63)
    const bf16x8 bQ0 = *(const bf16x8*)(Qp + l16 * HD + quad * 8);
    const bf16x8 bQ1 = *(const bf16x8*)(Qp + l16 * HD + 32 + quad * 8);

    // staging: wave w covers rows w*8..w*8+7 of K (keys) and V^T (d);
    // thread covers row = w*8 + (lane>>3), chunk slot cs = lane&7,
    // source chunk c = (cs - row)&7  (chunk' = (chunk+row)&7 swizzle)
    const int srow = w * 8 + (lane >> 3);
    const int c = ((lane & 7) - srow) & 7;
    const bf16* gK = Kp + (size_t)srow * HD + c * 8;
    const bf16* gV = Vp + (size_t)srow * SS + c * 8;
    bf16* const lK = &Ks[0][w * 512];
    bf16* const lV = &Vs[0][w * 512];

#define STAGE(BUF, KB) do {                                              \
        gld_lds16(gK + (size_t)(KB) * HD, lK + (BUF) * 4096);            \
        gld_lds16(gV + (KB),              lV + (BUF) * 4096);            \
    } while (0)

    // LDS read element-offsets, loop-invariant (16*mi == 0 mod 8 drops out)
    const int offK0 = l16 * 64 + ((quad + l16) & 7) * 8;
    const int offK1 = l16 * 64 + ((quad + 4 + l16) & 7) * 8;
    int offV[4];
#pragma unroll
    for (int mi = 0; mi < 4; ++mi)
        offV[mi] = l16 * 64 + ((((quad >> 1) + 2 * mi + l16) & 7) * 8)
                 + (quad & 1) * 4;

    const bf16* const KsB = &Ks[0][0];
    const bf16* const VsB = &Vs[0][0];

    f32x4 accO[4] = {{0,0,0,0},{0,0,0,0},{0,0,0,0},{0,0,0,0}};
    float Lr = 0.f;

    // One 64-key tile: QK^T (16x16x32) -> mask -> p=exp2(s) in-register ->
    // PV (16x16x16, P register-resident). BUF is compile-time.
#define TILE(BUF, KB) do {                                                   \
        f32x4 St[4] = {{0,0,0,0},{0,0,0,0},{0,0,0,0},{0,0,0,0}};             \
        _Pragma("unroll")                                                    \
        for (int mi = 0; mi < 4; ++mi) {                                     \
            const bf16x8 a0 = *(const bf16x8*)(KsB + (BUF) * 4096            \
                                               + mi * 1024 + offK0);         \
            const bf16x8 a1 = *(const bf16x8*)(KsB + (BUF) * 4096            \
                                               + mi * 1024 + offK1);         \
            St[mi] = __builtin_amdgcn_mfma_f32_16x16x32_bf16(                \
                a0, bQ0, St[mi], 0, 0, 0);                                   \
            St[mi] = __builtin_amdgcn_mfma_f32_16x16x32_bf16(                \
                a1, bQ1, St[mi], 0, 0, 0);                                   \
        }                                                                    \
        if ((KB) + 63 > q0w) {                                               \
            _Pragma("unroll")                                                \
            for (int mi = 0; mi < 4; ++mi)                                   \
                _Pragma("unroll")                                            \
                for (int rr = 0; rr < 4; ++rr)                               \
                    if ((KB) + mi * 16 + quad * 4 + rr > qrow)               \
                        St[mi][rr] = -1e30f;                                 \
        }                                                                    \
        float rs = 0.f;                                                      \
        short4v pb[4];                                                       \
        _Pragma("unroll")                                                    \
        for (int mi = 0; mi < 4; ++mi) {                                     \
            bf16x4 pk;                                                       \
            _Pragma("unroll")                                                \
            for (int rr = 0; rr < 4; ++rr) {                                 \
                const float p = EXP2F(St[mi][rr]);                           \
                rs += p;                                                     \
                pk[rr] = (bf16)p;                                            \
            }                                                                \
            pb[mi] = __builtin_bit_cast(short4v, pk);                        \
        }                                                                    \
        rs += __shfl_xor(rs, 16);                                            \
        rs += __shfl_xor(rs, 32);                                            \
        Lr += rs;                                                            \
        _Pragma("unroll")                                                    \
        for (int mi = 0; mi < 4; ++mi) {                                     \
            _Pragma("unroll")                                                 \
            for (int db = 0; db < 4; ++db) {                                 \
                const bf16x4 aV = *(const bf16x4*)(VsB + (BUF) * 4096        \
                                                   + db * 1024 + offV[mi]);  \
                accO[db] = pv_mfma16(aV, pb[mi], accO[db]);                  \
            }                                                                \
        }                                                                    \
    } while (0)

    STAGE(0, 0);
    int kb = 0;
    for (int kt = 0; kt < nkt; kt += 2) {
        __syncthreads();                       // buf0 staged / buf0 free
        STAGE(1, kb + 64);                     // kt+1 < nkt always (nkt even)
        TILE(0, kb);
        __syncthreads();                       // buf1 staged / buf1 free
        if (kt + 2 < nkt) {
            STAGE(0, kb + 128);
            TILE(1, kb + 64);
        } else {
            // last tile: keys q0b+64..q0b+127 -> dead for waves 0-3
            if (w >= 4) TILE(1, kb + 64);
        }
        kb += 128;
    }
#undef TILE
#undef STAGE

    // ---- epilogue ----------------------------------------------------------
    const float rinv = 1.0f / Lr;
    const int b = bh >> 4, h = bh & (HH - 1);
    bf16* op = ctx + ((size_t)(b * SS + q0w + l16)) * DD + h * HD;
#pragma unroll
    for (int db = 0; db < 4; ++db) {
        bf16x4 o;
#pragma unroll
        for (int rr = 0; rr < 4; ++rr) o[rr] = (bf16)(accO[db][rr] * rinv);
        *(bf16x4*)(op + db * 16 + quad * 4) = o;
    }
}

// ---------------------------------------------------------------------------
extern "C" void kernel_launch(void* const* d_in, const int* in_sizes, int n_in,
                              void* d_out, int out_size, void* d_ws, size_t ws_size,
                              hipStream_t stream)
{
    const float* x  = (const float*)d_in[0];
    const float* Wq = (const float*)d_in[1];
    const float* Wk = (const float*)d_in[2];
    const float* Wv = (const float*)d_in[3];
    const float* Wo = (const float*)d_in[4];
    const float* bo = (const float*)d_in[5];
    float* out = (float*)d_out;

    const size_t chunk = (size_t)MM * DD;
    bf16* xb  = (bf16*)d_ws;
    bf16* Wt  = xb + chunk;
    bf16* Qb  = Wt + 4 * (size_t)DD * DD;
    bf16* Kb  = Qb + chunk;
    bf16* Vb  = Kb + chunk;
    bf16* ctx = Vb + chunk;

    prep<<<dim3(32, 32, 6), dim3(256), 0, stream>>>(x, Wq, Wk, Wv, Wo, xb, Wt);

    gemm_qkv<<<dim3(DD / 128, MM / 128, 3), dim3(256), 0, stream>>>(xb, Wt, Qb, Kb, Vb);

    attn_flash<<<dim3(BB * HH * (SS / 128)), dim3(512), 0, stream>>>(Qb, Kb, Vb, ctx);

    gemm_out<<<dim3(DD / 128, MM / 128), dim3(256), 0, stream>>>(
        ctx, Wt + 3 * (size_t)DD * DD, bo, out);
}